// Round 8
// baseline (441.133 us; speedup 1.0000x reference)
//
#include <hip/hip_runtime.h>
#include <hip/hip_bf16.h>
#include <math.h>

#define NTOK   1024
#define DMODEL 1024
#define NHEADS 16
#define DHEAD  64

typedef __attribute__((ext_vector_type(8))) short short8;
typedef __attribute__((ext_vector_type(4))) float floatx4;
#define MFMA(a,b,c) __builtin_amdgcn_mfma_f32_16x16x32_bf16(a,b,c,0,0,0)

// split f into bf16 hi + bf16 lo (hi = RNE(f), lo = RNE(f - hi)); hi+lo ~ 16-bit mantissa
__device__ __forceinline__ void bf16_split(float f, ushort& h, ushort& l) {
    unsigned u = __float_as_uint(f);
    unsigned hr = (u + 0x7FFFu + ((u >> 16) & 1u)) >> 16;
    h = (ushort)hr;
    float fh = __uint_as_float(hr << 16);
    float res = f - fh;
    unsigned u2 = __float_as_uint(res);
    l = (ushort)((u2 + 0x7FFFu + ((u2 >> 16) & 1u)) >> 16);
}

// LDS chunk swizzle (16B chunks within a 128B row): 2-way-free banks
__device__ __forceinline__ int swzK(int r) { return (r & 7) ^ ((r >> 3) & 7); }

// ---------------------------------------------------------------------------
// Kernel 1: geometric bias MLP (unchanged, known-good).
// ---------------------------------------------------------------------------
__global__ __launch_bounds__(256) void bias_kernel(
    const float* __restrict__ xyz,
    const float* __restrict__ W1, const float* __restrict__ b1,
    const float* __restrict__ W2, const float* __restrict__ b2,
    float* __restrict__ attnO)
{
    __shared__ float wbuf[656];
    int tid = threadIdx.x;
    for (int i = tid; i < 656; i += 256) {
        float v;
        if (i < 96)       v = W1[i];
        else if (i < 128) v = b1[i - 96];
        else if (i < 640) v = W2[i - 128];
        else              v = b2[i - 640];
        wbuf[i] = v;
    }
    __syncthreads();
    const float* w1s = wbuf;
    const float* b1s = wbuf + 96;
    const float* w2s = wbuf + 128;
    const float* b2s = wbuf + 640;

    int j = blockIdx.x * 256 + tid;
    int i = blockIdx.y;
    int b = blockIdx.z;

    float xi0 = xyz[((size_t)b * NTOK + i) * 3 + 0];
    float xi1 = xyz[((size_t)b * NTOK + i) * 3 + 1];
    float xi2 = xyz[((size_t)b * NTOK + i) * 3 + 2];
    float d0 = xi0 - xyz[((size_t)b * NTOK + j) * 3 + 0];
    float d1 = xi1 - xyz[((size_t)b * NTOK + j) * 3 + 1];
    float d2 = xi2 - xyz[((size_t)b * NTOK + j) * 3 + 2];

    float h[32];
#pragma unroll
    for (int hh = 0; hh < 32; ++hh) {
        float v = b1s[hh] + d0 * w1s[hh] + d1 * w1s[32 + hh] + d2 * w1s[64 + hh];
        h[hh] = fmaxf(v, 0.f);
    }
    size_t base = (size_t)b * NHEADS * 1048576 + (size_t)i * 1024 + j;
#pragma unroll
    for (int hd = 0; hd < NHEADS; ++hd) {
        float acc = b2s[hd];
#pragma unroll
        for (int hh = 0; hh < 32; ++hh) acc += h[hh] * w2s[hh * 16 + hd];
        attnO[base + (size_t)hd * 1048576] = acc;
    }
}

// ---------------------------------------------------------------------------
// Kernel C1: x fp32 -> xh/xl bf16 (same [2048][1024] layout).
// ---------------------------------------------------------------------------
__global__ __launch_bounds__(256) void convx_kernel(
    const float* __restrict__ x, ushort* __restrict__ xh, ushort* __restrict__ xl)
{
    int id = blockIdx.x * 256 + threadIdx.x;      // 0..524287, 4 floats each
    float4 v = ((const float4*)x)[id];
    ushort h0,h1,h2,h3,l0,l1,l2,l3;
    bf16_split(v.x,h0,l0); bf16_split(v.y,h1,l1);
    bf16_split(v.z,h2,l2); bf16_split(v.w,h3,l3);
    ushort4 hv; hv.x=h0; hv.y=h1; hv.z=h2; hv.w=h3;
    ushort4 lv; lv.x=l0; lv.y=l1; lv.z=l2; lv.w=l3;
    ((ushort4*)xh)[id] = hv;
    ((ushort4*)xl)[id] = lv;
}

// ---------------------------------------------------------------------------
// Kernel C2: weight transpose+convert. z=0..2: Wq/Wk/Wv -> Wcat_t[3072][1024];
// z=3: Wo -> Wot[1024][1024]. Output layout: [n][k] bf16 hi/lo.
// ---------------------------------------------------------------------------
__global__ __launch_bounds__(256) void convw_kernel(
    const float* __restrict__ Wq, const float* __restrict__ Wk,
    const float* __restrict__ Wv, const float* __restrict__ Wo,
    ushort* __restrict__ Wcth, ushort* __restrict__ Wctl,
    ushort* __restrict__ Woth, ushort* __restrict__ Wotl)
{
    __shared__ float t[64][65];
    int z = blockIdx.z;
    const float* W = (z == 0) ? Wq : (z == 1) ? Wk : (z == 2) ? Wv : Wo;
    int n0 = blockIdx.x * 64, k0 = blockIdx.y * 64;
    int tid = threadIdx.x;
    int c4 = tid & 15, rr = tid >> 4;
#pragma unroll
    for (int t4 = 0; t4 < 4; ++t4) {
        int row = rr + t4 * 16;                  // k-local
        float4 v = *(const float4*)&W[(size_t)(k0 + row) * 1024 + n0 + c4 * 4];
        t[row][c4 * 4 + 0] = v.x; t[row][c4 * 4 + 1] = v.y;
        t[row][c4 * 4 + 2] = v.z; t[row][c4 * 4 + 3] = v.w;
    }
    __syncthreads();
    ushort* oh = (z < 3) ? Wcth : Woth;
    ushort* ol = (z < 3) ? Wctl : Wotl;
    int nbase = (z < 3) ? z * 1024 : 0;
#pragma unroll
    for (int t4 = 0; t4 < 4; ++t4) {
        int nl = rr + t4 * 16;                   // n-local
        int kk = c4 * 4;
        ushort4 hv, lv;
        ushort h, l;
        bf16_split(t[kk + 0][nl], h, l); hv.x = h; lv.x = l;
        bf16_split(t[kk + 1][nl], h, l); hv.y = h; lv.y = l;
        bf16_split(t[kk + 2][nl], h, l); hv.z = h; lv.z = l;
        bf16_split(t[kk + 3][nl], h, l); hv.w = h; lv.w = l;
        size_t o = (size_t)(nbase + n0 + nl) * 1024 + k0 + kk;
        *(ushort4*)&oh[o] = hv;
        *(ushort4*)&ol[o] = lv;
    }
}

// ---------------------------------------------------------------------------
// Kernel G: split-bf16 MFMA GEMM, LDS-staged via global_load_lds (unchanged).
// ---------------------------------------------------------------------------
__global__ __launch_bounds__(256) void mm_kernel(
    const ushort* __restrict__ Ah, const ushort* __restrict__ Al,
    const ushort* __restrict__ Bh, const ushort* __restrict__ Bl,
    const float* __restrict__ bq, const float* __restrict__ bk,
    const float* __restrict__ bv,
    float* __restrict__ out,
    ushort* __restrict__ qh, ushort* __restrict__ ql,
    ushort* __restrict__ kh, ushort* __restrict__ kl,
    ushort* __restrict__ vth, ushort* __restrict__ vtl,
    int mode)
{
    __shared__ ushort lds[4][64][64];            // 32 KB

    int n0 = blockIdx.x * 64;
    int m0 = blockIdx.y * 64;
    int w = threadIdx.x >> 6, l = threadIdx.x & 63;
    int li = l & 15, lg = l >> 4;
    int wm = w >> 1, wn = w & 1;

    const ushort* gbase;
    if      (w == 0) gbase = Ah + (size_t)m0 * 1024;
    else if (w == 1) gbase = Al + (size_t)m0 * 1024;
    else if (w == 2) gbase = Bh + (size_t)n0 * 1024;
    else             gbase = Bl + (size_t)n0 * 1024;
    ushort* lbase = &lds[w][0][0];
    int srow = l >> 3;                           // 0..7
    int sc   = l & 7;                            // 16B chunk

    floatx4 acc[2][2];
#pragma unroll
    for (int i = 0; i < 2; ++i)
#pragma unroll
        for (int j = 0; j < 2; ++j) acc[i][j] = (floatx4){0.f, 0.f, 0.f, 0.f};

    for (int ks = 0; ks < 16; ++ks) {
        int k0 = ks * 64;
#pragma unroll
        for (int t = 0; t < 8; ++t) {
            int rl = t * 8 + srow;
            int cs = sc ^ swzK(rl);
            const ushort* g = gbase + (size_t)rl * 1024 + k0 + cs * 8;
            __builtin_amdgcn_global_load_lds(
                (const __attribute__((address_space(1))) unsigned int*)g,
                (__attribute__((address_space(3))) unsigned int*)(lbase + t * 512),
                16, 0, 0);
        }
        __syncthreads();
#pragma unroll
        for (int kk = 0; kk < 2; ++kk) {
            short8 a[2][2], b2[2][2];
#pragma unroll
            for (int f = 0; f < 2; ++f) {
                int ra = wm * 32 + f * 16 + li;
                int ca = ((kk * 4 + lg) ^ swzK(ra)) * 8;
                a[f][0] = *(const short8*)&lds[0][ra][ca];
                a[f][1] = *(const short8*)&lds[1][ra][ca];
                int rb = wn * 32 + f * 16 + li;
                int cb = ((kk * 4 + lg) ^ swzK(rb)) * 8;
                b2[f][0] = *(const short8*)&lds[2][rb][cb];
                b2[f][1] = *(const short8*)&lds[3][rb][cb];
            }
#pragma unroll
            for (int fm = 0; fm < 2; ++fm)
#pragma unroll
                for (int fn = 0; fn < 2; ++fn) {
                    acc[fm][fn] = MFMA(a[fm][0], b2[fn][0], acc[fm][fn]);
                    acc[fm][fn] = MFMA(a[fm][0], b2[fn][1], acc[fm][fn]);
                    acc[fm][fn] = MFMA(a[fm][1], b2[fn][0], acc[fm][fn]);
                }
        }
        __syncthreads();
    }

    if (mode == 0) {
#pragma unroll
        for (int fm = 0; fm < 2; ++fm)
#pragma unroll
            for (int fn = 0; fn < 2; ++fn) {
                int col = n0 + wn * 32 + fn * 16 + li;
                float bval = bq[col];
#pragma unroll
                for (int r = 0; r < 4; ++r) {
                    int row = m0 + wm * 32 + fm * 16 + lg * 4 + r;
                    out[(size_t)row * 1024 + col] = acc[fm][fn][r] + bval;
                }
            }
    } else {
        int z = n0 >> 10;
        const float* bp = (z == 0) ? bq : (z == 1) ? bk : bv;
#pragma unroll
        for (int fm = 0; fm < 2; ++fm)
#pragma unroll
            for (int fn = 0; fn < 2; ++fn) {
                int col = n0 + wn * 32 + fn * 16 + li;
                int nloc = col & 1023;
                int hd = nloc >> 6, d = nloc & 63;
                float bval = bp[nloc];
#pragma unroll
                for (int r = 0; r < 4; ++r) {
                    int row = m0 + wm * 32 + fm * 16 + lg * 4 + r;
                    int b = row >> 10, nn = row & 1023;
                    int bh = b * NHEADS + hd;
                    float v = acc[fm][fn][r] + bval;
                    ushort h, lo; bf16_split(v, h, lo);
                    if (z == 0) {
                        size_t o = ((size_t)bh * NTOK + nn) * DHEAD + d;
                        qh[o] = h; ql[o] = lo;
                    } else if (z == 1) {
                        size_t o = ((size_t)bh * NTOK + nn) * DHEAD + d;
                        kh[o] = h; kl[o] = lo;
                    } else {
                        size_t o = ((size_t)bh * DHEAD + d) * NTOK + nn;
                        vth[o] = h; vtl[o] = lo;
                    }
                }
            }
    }
}

// ---------------------------------------------------------------------------
// Kernel AT (fused): scores + softmax + PV. Block = (qt 16 rows, h, b);
// 4 waves; wave w owns keys [w*256, w*256+256).
//   S = (q.k^T)/8 + bias (read from attnO) -> softmax -> P fp32 to attnO
//   then P staged transposed (bf16 hi/lo) in wave-private LDS, PV via MFMA,
//   cross-wave reduce in aliased LDS, aw written bf16 hi/lo.
// smem: [0,34816) pbuf 4 waves x {hi,lo} x [16][136] ushort (chunked 128 keys)
//       [0,17408) obuf alias after barrier: [4][16][68] float
//       [34816,35072) redM, [35072,35328) redS
// ---------------------------------------------------------------------------
__global__ __launch_bounds__(256) void attn_fused_kernel(
    const ushort* __restrict__ qh, const ushort* __restrict__ ql,
    const ushort* __restrict__ kh, const ushort* __restrict__ kl,
    const ushort* __restrict__ vth, const ushort* __restrict__ vtl,
    float* __restrict__ attnO,
    ushort* __restrict__ awh, ushort* __restrict__ awl)
{
    __shared__ char smem[35328];
    float* obuf = (float*)smem;                       // [4][16][68], alias of pbuf
    float* redM = (float*)(smem + 34816);             // [4][16]
    float* redS = (float*)(smem + 35072);             // [4][16]

    int qt = blockIdx.x, hd = blockIdx.y, b = blockIdx.z;
    int bh = b * NHEADS + hd;
    int w = threadIdx.x >> 6, l = threadIdx.x & 63;
    int li = l & 15, lg = l >> 4;

    ushort* pbh = (ushort*)smem + (size_t)w * 4352;   // [16][136]
    ushort* pbl = pbh + 2176;

    size_t qoff = ((size_t)bh * NTOK + qt * 16 + li) * DHEAD + lg * 8;
    short8 q0h = *(const short8*)(qh + qoff);
    short8 q0l = *(const short8*)(ql + qoff);
    short8 q1h = *(const short8*)(qh + qoff + 32);
    short8 q1l = *(const short8*)(ql + qoff + 32);

    floatx4 acc[16];
#pragma unroll
    for (int jf = 0; jf < 16; ++jf) acc[jf] = (floatx4){0.f, 0.f, 0.f, 0.f};

    int jbase = w * 256;
#pragma unroll
    for (int jf = 0; jf < 16; ++jf) {
        size_t koff = ((size_t)bh * NTOK + jbase + jf * 16 + li) * DHEAD + lg * 8;
        short8 K0h = *(const short8*)(kh + koff);
        short8 K0l = *(const short8*)(kl + koff);
        short8 K1h = *(const short8*)(kh + koff + 32);
        short8 K1l = *(const short8*)(kl + koff + 32);
        acc[jf] = MFMA(q0h, K0h, acc[jf]);
        acc[jf] = MFMA(q0h, K0l, acc[jf]);
        acc[jf] = MFMA(q0l, K0h, acc[jf]);
        acc[jf] = MFMA(q1h, K1h, acc[jf]);
        acc[jf] = MFMA(q1h, K1l, acc[jf]);
        acc[jf] = MFMA(q1l, K1h, acc[jf]);
    }

    float* prow = attnO + ((size_t)bh * NTOK + qt * 16) * NTOK;

    float mloc[4] = {-1e30f, -1e30f, -1e30f, -1e30f};
#pragma unroll
    for (int jf = 0; jf < 16; ++jf)
#pragma unroll
        for (int r = 0; r < 4; ++r) {
            float s = acc[jf][r] * 0.125f
                    + prow[(size_t)(lg * 4 + r) * NTOK + jbase + jf * 16 + li];
            acc[jf][r] = s;
            mloc[r] = fmaxf(mloc[r], s);
        }
#pragma unroll
    for (int r = 0; r < 4; ++r) {
        float m = mloc[r];
        m = fmaxf(m, __shfl_xor(m, 1, 64));
        m = fmaxf(m, __shfl_xor(m, 2, 64));
        m = fmaxf(m, __shfl_xor(m, 4, 64));
        m = fmaxf(m, __shfl_xor(m, 8, 64));
        mloc[r] = m;
    }
    if (li == 0) {
#pragma unroll
        for (int r = 0; r < 4; ++r) redM[w * 16 + lg * 4 + r] = mloc[r];
    }
    __syncthreads();
    float M[4];
#pragma unroll
    for (int r = 0; r < 4; ++r) {
        int row = lg * 4 + r;
        M[r] = fmaxf(fmaxf(redM[0 + row], redM[16 + row]),
                     fmaxf(redM[32 + row], redM[48 + row]));
    }
    float sloc[4] = {0.f, 0.f, 0.f, 0.f};
#pragma unroll
    for (int jf = 0; jf < 16; ++jf)
#pragma unroll
        for (int r = 0; r < 4; ++r) {
            float e = __expf(acc[jf][r] - M[r]);
            acc[jf][r] = e;
            sloc[r] += e;
        }
#pragma unroll
    for (int r = 0; r < 4; ++r) {
        float s = sloc[r];
        s += __shfl_xor(s, 1, 64);
        s += __shfl_xor(s, 2, 64);
        s += __shfl_xor(s, 4, 64);
        s += __shfl_xor(s, 8, 64);
        sloc[r] = s;
    }
    if (li == 0) {
#pragma unroll
        for (int r = 0; r < 4; ++r) redS[w * 16 + lg * 4 + r] = sloc[r];
    }
    __syncthreads();
    float inv[4];
#pragma unroll
    for (int r = 0; r < 4; ++r) {
        int row = lg * 4 + r;
        inv[r] = 1.0f / (redS[0 + row] + redS[16 + row] +
                         redS[32 + row] + redS[48 + row]);
    }
    // normalize in-register and write P fp32 (mandatory output)
#pragma unroll
    for (int jf = 0; jf < 16; ++jf)
#pragma unroll
        for (int r = 0; r < 4; ++r) {
            float p = acc[jf][r] * inv[r];
            acc[jf][r] = p;
            prow[(size_t)(lg * 4 + r) * NTOK + jbase + jf * 16 + li] = p;
        }

    // ---- PV: stage P^T (bf16 hi/lo) in wave-private LDS, 2 chunks of 128 ----
    const ushort* vbh = vth + (size_t)bh * DHEAD * NTOK;
    const ushort* vbl = vtl + (size_t)bh * DHEAD * NTOK;
    floatx4 accv[4];
#pragma unroll
    for (int nf = 0; nf < 4; ++nf) accv[nf] = (floatx4){0.f, 0.f, 0.f, 0.f};

#pragma unroll
    for (int c = 0; c < 2; ++c) {
#pragma unroll
        for (int jf8 = 0; jf8 < 8; ++jf8) {
            int jf = c * 8 + jf8;
            int kloc = jf8 * 16 + li;
#pragma unroll
            for (int r = 0; r < 4; ++r) {
                int row = lg * 4 + r;
                ushort hh, ll; bf16_split(acc[jf][r], hh, ll);
                pbh[row * 136 + kloc] = hh;
                pbl[row * 136 + kloc] = ll;
            }
        }
        // same-wave LDS RAW: compiler inserts lgkmcnt wait
#pragma unroll
        for (int ks = 0; ks < 4; ++ks) {
            int koff_l = ks * 32 + lg * 8;               // within 128-chunk
            short8 Ah8 = *(const short8*)&pbh[li * 136 + koff_l];
            short8 Al8 = *(const short8*)&pbl[li * 136 + koff_l];
            size_t kg = (size_t)jbase + c * 128 + koff_l; // global key offset
#pragma unroll
            for (int nf = 0; nf < 4; ++nf) {
                short8 Bh8 = *(const short8*)(vbh + (size_t)(nf * 16 + li) * NTOK + kg);
                short8 Bl8 = *(const short8*)(vbl + (size_t)(nf * 16 + li) * NTOK + kg);
                accv[nf] = MFMA(Ah8, Bh8, accv[nf]);
                accv[nf] = MFMA(Ah8, Bl8, accv[nf]);
                accv[nf] = MFMA(Al8, Bh8, accv[nf]);
            }
        }
    }

    __syncthreads();   // all waves done with pbuf; obuf alias now safe
#pragma unroll
    for (int nf = 0; nf < 4; ++nf)
#pragma unroll
        for (int r = 0; r < 4; ++r)
            obuf[(w * 16 + lg * 4 + r) * 68 + nf * 16 + li] = accv[nf][r];
    __syncthreads();
    {
        int row = threadIdx.x >> 4, d0 = (threadIdx.x & 15) * 4;
        float s0 = 0.f, s1 = 0.f, s2 = 0.f, s3 = 0.f;
#pragma unroll
        for (int ww = 0; ww < 4; ++ww) {
            float4 t = *(const float4*)&obuf[(ww * 16 + row) * 68 + d0];
            s0 += t.x; s1 += t.y; s2 += t.z; s3 += t.w;
        }
        ushort4 hv, lv; ushort h, lo;
        bf16_split(s0, h, lo); hv.x = h; lv.x = lo;
        bf16_split(s1, h, lo); hv.y = h; lv.y = lo;
        bf16_split(s2, h, lo); hv.z = h; lv.z = lo;
        bf16_split(s3, h, lo); hv.w = h; lv.w = lo;
        size_t o = ((size_t)(b * NTOK + qt * 16 + row)) * DMODEL + hd * DHEAD + d0;
        *(ushort4*)&awh[o] = hv;
        *(ushort4*)&awl[o] = lv;
    }
}

// ---------------------------------------------------------------------------
extern "C" void kernel_launch(void* const* d_in, const int* in_sizes, int n_in,
                              void* d_out, int out_size, void* d_ws, size_t ws_size,
                              hipStream_t stream)
{
    const float* x   = (const float*)d_in[0];
    const float* xyz = (const float*)d_in[1];
    const float* Wq  = (const float*)d_in[2];
    const float* bq  = (const float*)d_in[3];
    const float* Wk  = (const float*)d_in[4];
    const float* bk  = (const float*)d_in[5];
    const float* Wv  = (const float*)d_in[6];
    const float* bv  = (const float*)d_in[7];
    const float* Wo  = (const float*)d_in[8];
    const float* bo  = (const float*)d_in[9];
    const float* W1  = (const float*)d_in[10];
    const float* b1  = (const float*)d_in[11];
    const float* W2  = (const float*)d_in[12];
    const float* b2  = (const float*)d_in[13];

    const size_t OUT_ELEMS = (size_t)2 * NTOK * DMODEL;     // 2,097,152
    float* out   = (float*)d_out;
    float* attnO = out + OUT_ELEMS;                          // [B,H,N,N]

    // workspace layout (bytes)
    char* ws = (char*)d_ws;
    ushort* Wcth = (ushort*)(ws);                            //  6 MB [3072][1024]
    ushort* Wctl = (ushort*)(ws + 6291456);                  //  6 MB
    ushort* Woth = (ushort*)(ws + 12582912);                 //  2 MB [1024][1024]
    ushort* Wotl = (ushort*)(ws + 14680064);                 //  2 MB
    ushort* qh   = (ushort*)(ws + 16777216);                 //  4 MB [bh][n][64]
    ushort* ql   = (ushort*)(ws + 20971520);
    ushort* kh   = (ushort*)(ws + 25165824);
    ushort* kl   = (ushort*)(ws + 29360128);
    ushort* vth  = (ushort*)(ws + 33554432);                 //  4 MB [bh][64][n]
    ushort* vtl  = (ushort*)(ws + 37748736);
    ushort* xh   = (ushort*)(ws + 41943040);                 //  4 MB [2048][1024]
    ushort* xl   = (ushort*)(ws + 46137344);                 //  ends at 48 MB
    // aw aliases the x buffers (x is dead after the QKV GEMM)
    ushort* awh  = xh;
    ushort* awl  = xl;

    // 1) bias MLP -> attn region of d_out
    bias_kernel<<<dim3(4, 1024, 2), 256, 0, stream>>>(xyz, W1, b1, W2, b2, attnO);
    // 2) input conversions
    convx_kernel<<<dim3(2048), 256, 0, stream>>>(x, xh, xl);
    convw_kernel<<<dim3(16, 16, 4), 256, 0, stream>>>(Wq, Wk, Wv, Wo,
                                                      Wcth, Wctl, Woth, Wotl);
    // 3) fused QKV projection (M=2048, N=3072), 64x64 tiles
    mm_kernel<<<dim3(48, 32), 256, 0, stream>>>(xh, xl, Wcth, Wctl,
                                                bq, bk, bv, nullptr,
                                                qh, ql, kh, kl, vth, vtl, 1);
    // 4) fused scores + softmax + PV -> attnO (P) and aw (bf16 hi/lo)
    attn_fused_kernel<<<dim3(64, NHEADS, 2), 256, 0, stream>>>(
        qh, ql, kh, kl, vth, vtl, attnO, awh, awl);
    // 5) output projection (M=2048, N=1024), 64x64 tiles
    mm_kernel<<<dim3(16, 32), 256, 0, stream>>>(awh, awl, Woth, Wotl,
                                                bo, bo, bo, out,
                                                nullptr, nullptr, nullptr, nullptr,
                                                nullptr, nullptr, 0);
}

// Round 9
// 438.335 us; speedup vs baseline: 1.0064x; 1.0064x over previous
//
#include <hip/hip_runtime.h>
#include <hip/hip_bf16.h>
#include <math.h>

#define NTOK   1024
#define DMODEL 1024
#define NHEADS 16
#define DHEAD  64

typedef __attribute__((ext_vector_type(8))) short short8;
typedef __attribute__((ext_vector_type(4))) float floatx4;
#define MFMA(a,b,c) __builtin_amdgcn_mfma_f32_16x16x32_bf16(a,b,c,0,0,0)

// split f into bf16 hi + bf16 lo (hi = RNE(f), lo = RNE(f - hi)); hi+lo ~ 16-bit mantissa
__device__ __forceinline__ void bf16_split(float f, ushort& h, ushort& l) {
    unsigned u = __float_as_uint(f);
    unsigned hr = (u + 0x7FFFu + ((u >> 16) & 1u)) >> 16;
    h = (ushort)hr;
    float fh = __uint_as_float(hr << 16);
    float res = f - fh;
    unsigned u2 = __float_as_uint(res);
    l = (ushort)((u2 + 0x7FFFu + ((u2 >> 16) & 1u)) >> 16);
}

// LDS chunk swizzle (16B chunks within a 128B row): 2-way-free banks
__device__ __forceinline__ int swzK(int r) { return (r & 7) ^ ((r >> 3) & 7); }

// ---------------------------------------------------------------------------
// Kernel 1: geometric bias MLP (unchanged, known-good).
// ---------------------------------------------------------------------------
__global__ __launch_bounds__(256) void bias_kernel(
    const float* __restrict__ xyz,
    const float* __restrict__ W1, const float* __restrict__ b1,
    const float* __restrict__ W2, const float* __restrict__ b2,
    float* __restrict__ attnO)
{
    __shared__ float wbuf[656];
    int tid = threadIdx.x;
    for (int i = tid; i < 656; i += 256) {
        float v;
        if (i < 96)       v = W1[i];
        else if (i < 128) v = b1[i - 96];
        else if (i < 640) v = W2[i - 128];
        else              v = b2[i - 640];
        wbuf[i] = v;
    }
    __syncthreads();
    const float* w1s = wbuf;
    const float* b1s = wbuf + 96;
    const float* w2s = wbuf + 128;
    const float* b2s = wbuf + 640;

    int j = blockIdx.x * 256 + tid;
    int i = blockIdx.y;
    int b = blockIdx.z;

    float xi0 = xyz[((size_t)b * NTOK + i) * 3 + 0];
    float xi1 = xyz[((size_t)b * NTOK + i) * 3 + 1];
    float xi2 = xyz[((size_t)b * NTOK + i) * 3 + 2];
    float d0 = xi0 - xyz[((size_t)b * NTOK + j) * 3 + 0];
    float d1 = xi1 - xyz[((size_t)b * NTOK + j) * 3 + 1];
    float d2 = xi2 - xyz[((size_t)b * NTOK + j) * 3 + 2];

    float h[32];
#pragma unroll
    for (int hh = 0; hh < 32; ++hh) {
        float v = b1s[hh] + d0 * w1s[hh] + d1 * w1s[32 + hh] + d2 * w1s[64 + hh];
        h[hh] = fmaxf(v, 0.f);
    }
    size_t base = (size_t)b * NHEADS * 1048576 + (size_t)i * 1024 + j;
#pragma unroll
    for (int hd = 0; hd < NHEADS; ++hd) {
        float acc = b2s[hd];
#pragma unroll
        for (int hh = 0; hh < 32; ++hh) acc += h[hh] * w2s[hh * 16 + hd];
        attnO[base + (size_t)hd * 1048576] = acc;
    }
}

// ---------------------------------------------------------------------------
// Kernel C1: x fp32 -> xh/xl bf16 (same [2048][1024] layout).
// ---------------------------------------------------------------------------
__global__ __launch_bounds__(256) void convx_kernel(
    const float* __restrict__ x, ushort* __restrict__ xh, ushort* __restrict__ xl)
{
    int id = blockIdx.x * 256 + threadIdx.x;      // 0..524287, 4 floats each
    float4 v = ((const float4*)x)[id];
    ushort h0,h1,h2,h3,l0,l1,l2,l3;
    bf16_split(v.x,h0,l0); bf16_split(v.y,h1,l1);
    bf16_split(v.z,h2,l2); bf16_split(v.w,h3,l3);
    ushort4 hv; hv.x=h0; hv.y=h1; hv.z=h2; hv.w=h3;
    ushort4 lv; lv.x=l0; lv.y=l1; lv.z=l2; lv.w=l3;
    ((ushort4*)xh)[id] = hv;
    ((ushort4*)xl)[id] = lv;
}

// ---------------------------------------------------------------------------
// Kernel C2: weight transpose+convert. z=0..2: Wq/Wk/Wv -> Wcat_t[3072][1024];
// z=3: Wo -> Wot[1024][1024]. Output layout: [n][k] bf16 hi/lo.
// ---------------------------------------------------------------------------
__global__ __launch_bounds__(256) void convw_kernel(
    const float* __restrict__ Wq, const float* __restrict__ Wk,
    const float* __restrict__ Wv, const float* __restrict__ Wo,
    ushort* __restrict__ Wcth, ushort* __restrict__ Wctl,
    ushort* __restrict__ Woth, ushort* __restrict__ Wotl)
{
    __shared__ float t[64][65];
    int z = blockIdx.z;
    const float* W = (z == 0) ? Wq : (z == 1) ? Wk : (z == 2) ? Wv : Wo;
    int n0 = blockIdx.x * 64, k0 = blockIdx.y * 64;
    int tid = threadIdx.x;
    int c4 = tid & 15, rr = tid >> 4;
#pragma unroll
    for (int t4 = 0; t4 < 4; ++t4) {
        int row = rr + t4 * 16;                  // k-local
        float4 v = *(const float4*)&W[(size_t)(k0 + row) * 1024 + n0 + c4 * 4];
        t[row][c4 * 4 + 0] = v.x; t[row][c4 * 4 + 1] = v.y;
        t[row][c4 * 4 + 2] = v.z; t[row][c4 * 4 + 3] = v.w;
    }
    __syncthreads();
    ushort* oh = (z < 3) ? Wcth : Woth;
    ushort* ol = (z < 3) ? Wctl : Wotl;
    int nbase = (z < 3) ? z * 1024 : 0;
#pragma unroll
    for (int t4 = 0; t4 < 4; ++t4) {
        int nl = rr + t4 * 16;                   // n-local
        int kk = c4 * 4;
        ushort4 hv, lv;
        ushort h, l;
        bf16_split(t[kk + 0][nl], h, l); hv.x = h; lv.x = l;
        bf16_split(t[kk + 1][nl], h, l); hv.y = h; lv.y = l;
        bf16_split(t[kk + 2][nl], h, l); hv.z = h; lv.z = l;
        bf16_split(t[kk + 3][nl], h, l); hv.w = h; lv.w = l;
        size_t o = (size_t)(nbase + n0 + nl) * 1024 + k0 + kk;
        *(ushort4*)&oh[o] = hv;
        *(ushort4*)&ol[o] = lv;
    }
}

// ---------------------------------------------------------------------------
// Kernel G: split-bf16 MFMA GEMM, LDS-staged via global_load_lds (unchanged).
// ---------------------------------------------------------------------------
__global__ __launch_bounds__(256) void mm_kernel(
    const ushort* __restrict__ Ah, const ushort* __restrict__ Al,
    const ushort* __restrict__ Bh, const ushort* __restrict__ Bl,
    const float* __restrict__ bq, const float* __restrict__ bk,
    const float* __restrict__ bv,
    float* __restrict__ out,
    ushort* __restrict__ qh, ushort* __restrict__ ql,
    ushort* __restrict__ kh, ushort* __restrict__ kl,
    ushort* __restrict__ vth, ushort* __restrict__ vtl,
    int mode)
{
    __shared__ ushort lds[4][64][64];            // 32 KB

    int n0 = blockIdx.x * 64;
    int m0 = blockIdx.y * 64;
    int w = threadIdx.x >> 6, l = threadIdx.x & 63;
    int li = l & 15, lg = l >> 4;
    int wm = w >> 1, wn = w & 1;

    const ushort* gbase;
    if      (w == 0) gbase = Ah + (size_t)m0 * 1024;
    else if (w == 1) gbase = Al + (size_t)m0 * 1024;
    else if (w == 2) gbase = Bh + (size_t)n0 * 1024;
    else             gbase = Bl + (size_t)n0 * 1024;
    ushort* lbase = &lds[w][0][0];
    int srow = l >> 3;                           // 0..7
    int sc   = l & 7;                            // 16B chunk

    floatx4 acc[2][2];
#pragma unroll
    for (int i = 0; i < 2; ++i)
#pragma unroll
        for (int j = 0; j < 2; ++j) acc[i][j] = (floatx4){0.f, 0.f, 0.f, 0.f};

    for (int ks = 0; ks < 16; ++ks) {
        int k0 = ks * 64;
#pragma unroll
        for (int t = 0; t < 8; ++t) {
            int rl = t * 8 + srow;
            int cs = sc ^ swzK(rl);
            const ushort* g = gbase + (size_t)rl * 1024 + k0 + cs * 8;
            __builtin_amdgcn_global_load_lds(
                (const __attribute__((address_space(1))) unsigned int*)g,
                (__attribute__((address_space(3))) unsigned int*)(lbase + t * 512),
                16, 0, 0);
        }
        __syncthreads();
#pragma unroll
        for (int kk = 0; kk < 2; ++kk) {
            short8 a[2][2], b2[2][2];
#pragma unroll
            for (int f = 0; f < 2; ++f) {
                int ra = wm * 32 + f * 16 + li;
                int ca = ((kk * 4 + lg) ^ swzK(ra)) * 8;
                a[f][0] = *(const short8*)&lds[0][ra][ca];
                a[f][1] = *(const short8*)&lds[1][ra][ca];
                int rb = wn * 32 + f * 16 + li;
                int cb = ((kk * 4 + lg) ^ swzK(rb)) * 8;
                b2[f][0] = *(const short8*)&lds[2][rb][cb];
                b2[f][1] = *(const short8*)&lds[3][rb][cb];
            }
#pragma unroll
            for (int fm = 0; fm < 2; ++fm)
#pragma unroll
                for (int fn = 0; fn < 2; ++fn) {
                    acc[fm][fn] = MFMA(a[fm][0], b2[fn][0], acc[fm][fn]);
                    acc[fm][fn] = MFMA(a[fm][0], b2[fn][1], acc[fm][fn]);
                    acc[fm][fn] = MFMA(a[fm][1], b2[fn][0], acc[fm][fn]);
                }
        }
        __syncthreads();
    }

    if (mode == 0) {
#pragma unroll
        for (int fm = 0; fm < 2; ++fm)
#pragma unroll
            for (int fn = 0; fn < 2; ++fn) {
                int col = n0 + wn * 32 + fn * 16 + li;
                float bval = bq[col];
#pragma unroll
                for (int r = 0; r < 4; ++r) {
                    int row = m0 + wm * 32 + fm * 16 + lg * 4 + r;
                    out[(size_t)row * 1024 + col] = acc[fm][fn][r] + bval;
                }
            }
    } else {
        int z = n0 >> 10;
        const float* bp = (z == 0) ? bq : (z == 1) ? bk : bv;
#pragma unroll
        for (int fm = 0; fm < 2; ++fm)
#pragma unroll
            for (int fn = 0; fn < 2; ++fn) {
                int col = n0 + wn * 32 + fn * 16 + li;
                int nloc = col & 1023;
                int hd = nloc >> 6, d = nloc & 63;
                float bval = bp[nloc];
#pragma unroll
                for (int r = 0; r < 4; ++r) {
                    int row = m0 + wm * 32 + fm * 16 + lg * 4 + r;
                    int b = row >> 10, nn = row & 1023;
                    int bh = b * NHEADS + hd;
                    float v = acc[fm][fn][r] + bval;
                    ushort h, lo; bf16_split(v, h, lo);
                    if (z == 0) {
                        size_t o = ((size_t)bh * NTOK + nn) * DHEAD + d;
                        qh[o] = h; ql[o] = lo;
                    } else if (z == 1) {
                        size_t o = ((size_t)bh * NTOK + nn) * DHEAD + d;
                        kh[o] = h; kl[o] = lo;
                    } else {
                        size_t o = ((size_t)bh * DHEAD + d) * NTOK + nn;
                        vth[o] = h; vtl[o] = lo;
                    }
                }
            }
    }
}

// ---------------------------------------------------------------------------
// Kernel AT (fused v2): swapped QK^T + permuted K rows -> lane-local PV.
// Block = (qt 16 rows, h, b); 4 waves; wave w owns keys [w*256, w*256+256).
//   acc[jf] = mfma(K_perm, Q): lane (li,lg) holds S[q=li][key complex]:
//     acc[2t][r]   = S[li][jbase + t*32 + lg*8 + r]
//     acc[2t+1][r] = S[li][jbase + t*32 + lg*8 + 4 + r]
//   -> scalar softmax per lane (row = li), float4 bias/P IO,
//   -> PV A-frag built lane-locally (8 consecutive keys), K=32 MFMA vs V^T.
// LDS: obuf [4][16][68] f32 + redM/redS = ~18 KB; 3 barriers.
// ---------------------------------------------------------------------------
__global__ __launch_bounds__(256) void attn_fused_kernel(
    const ushort* __restrict__ qh, const ushort* __restrict__ ql,
    const ushort* __restrict__ kh, const ushort* __restrict__ kl,
    const ushort* __restrict__ vth, const ushort* __restrict__ vtl,
    float* __restrict__ attnO,
    ushort* __restrict__ awh, ushort* __restrict__ awl)
{
    __shared__ float obuf[4 * 16 * 68];               // 17408 B
    __shared__ float redM[4][16];
    __shared__ float redS[4][16];

    int qt = blockIdx.x, hd = blockIdx.y, b = blockIdx.z;
    int bh = b * NHEADS + hd;
    int w = threadIdx.x >> 6, l = threadIdx.x & 63;
    int li = l & 15, lg = l >> 4;
    int jbase = w * 256;

    // Q fragments (B operand): B-row = q = qt*16 + li
    size_t qoff = ((size_t)bh * NTOK + qt * 16 + li) * DHEAD + lg * 8;
    short8 q0h = *(const short8*)(qh + qoff);
    short8 q0l = *(const short8*)(ql + qoff);
    short8 q1h = *(const short8*)(qh + qoff + 32);
    short8 q1l = *(const short8*)(ql + qoff + 32);

    floatx4 acc[16];
#pragma unroll
    for (int jf = 0; jf < 16; ++jf) acc[jf] = (floatx4){0.f, 0.f, 0.f, 0.f};

    // ---- QK^T (swapped operands, permuted K rows) ----
#pragma unroll
    for (int t = 0; t < 8; ++t)
#pragma unroll
        for (int half = 0; half < 2; ++half) {
            int jf = t * 2 + half;
            int krow = jbase + t * 32 + ((li >> 2) << 3) + half * 4 + (li & 3);
            size_t koff = ((size_t)bh * NTOK + krow) * DHEAD + lg * 8;
            short8 K0h = *(const short8*)(kh + koff);
            short8 K0l = *(const short8*)(kl + koff);
            short8 K1h = *(const short8*)(kh + koff + 32);
            short8 K1l = *(const short8*)(kl + koff + 32);
            acc[jf] = MFMA(K0h, q0h, acc[jf]);
            acc[jf] = MFMA(K0h, q0l, acc[jf]);
            acc[jf] = MFMA(K0l, q0h, acc[jf]);
            acc[jf] = MFMA(K1h, q1h, acc[jf]);
            acc[jf] = MFMA(K1h, q1l, acc[jf]);
            acc[jf] = MFMA(K1l, q1h, acc[jf]);
        }

    float* prow = attnO + ((size_t)bh * NTOK + qt * 16) * NTOK;

    // ---- bias add (float4) + row max (scalar: all lane values are row li) ----
    float m = -1e30f;
#pragma unroll
    for (int t = 0; t < 8; ++t) {
        const float* bp = prow + (size_t)li * NTOK + jbase + t * 32 + lg * 8;
        float4 ba = *(const float4*)bp;
        float4 bb = *(const float4*)(bp + 4);
        float bav[4] = {ba.x, ba.y, ba.z, ba.w};
        float bbv[4] = {bb.x, bb.y, bb.z, bb.w};
#pragma unroll
        for (int r = 0; r < 4; ++r) {
            float s0 = acc[2 * t][r] * 0.125f + bav[r];
            float s1 = acc[2 * t + 1][r] * 0.125f + bbv[r];
            acc[2 * t][r] = s0;
            acc[2 * t + 1][r] = s1;
            m = fmaxf(m, fmaxf(s0, s1));
        }
    }
    m = fmaxf(m, __shfl_xor(m, 16, 64));
    m = fmaxf(m, __shfl_xor(m, 32, 64));
    if (lg == 0) redM[w][li] = m;
    __syncthreads();
    float M = fmaxf(fmaxf(redM[0][li], redM[1][li]),
                    fmaxf(redM[2][li], redM[3][li]));

    float s = 0.f;
#pragma unroll
    for (int jf = 0; jf < 16; ++jf)
#pragma unroll
        for (int r = 0; r < 4; ++r) {
            float e = __expf(acc[jf][r] - M);
            acc[jf][r] = e;
            s += e;
        }
    s += __shfl_xor(s, 16, 64);
    s += __shfl_xor(s, 32, 64);
    if (lg == 0) redS[w][li] = s;
    __syncthreads();
    float inv = 1.0f / (redS[0][li] + redS[1][li] + redS[2][li] + redS[3][li]);

    // ---- normalize, write P (float4), PV with lane-local A-frags ----
    const ushort* vbh = vth + (size_t)bh * DHEAD * NTOK;
    const ushort* vbl = vtl + (size_t)bh * DHEAD * NTOK;
    floatx4 accv[4];
#pragma unroll
    for (int nf = 0; nf < 4; ++nf) accv[nf] = (floatx4){0.f, 0.f, 0.f, 0.f};

#pragma unroll
    for (int t = 0; t < 8; ++t) {
        float pa[4], pb[4];
#pragma unroll
        for (int r = 0; r < 4; ++r) {
            pa[r] = acc[2 * t][r] * inv;
            pb[r] = acc[2 * t + 1][r] * inv;
        }
        float* pw = prow + (size_t)li * NTOK + jbase + t * 32 + lg * 8;
        *(float4*)pw = make_float4(pa[0], pa[1], pa[2], pa[3]);
        *(float4*)(pw + 4) = make_float4(pb[0], pb[1], pb[2], pb[3]);

        short8 Ah8, Al8;
#pragma unroll
        for (int e = 0; e < 4; ++e) {
            ushort hh, ll;
            bf16_split(pa[e], hh, ll); Ah8[e] = (short)hh; Al8[e] = (short)ll;
            bf16_split(pb[e], hh, ll); Ah8[4 + e] = (short)hh; Al8[4 + e] = (short)ll;
        }
        size_t kg = (size_t)jbase + t * 32 + lg * 8;
#pragma unroll
        for (int nf = 0; nf < 4; ++nf) {
            const ushort* vph = vbh + (size_t)(nf * 16 + li) * NTOK + kg;
            const ushort* vpl = vbl + (size_t)(nf * 16 + li) * NTOK + kg;
            short8 Bh8 = *(const short8*)vph;
            short8 Bl8 = *(const short8*)vpl;
            accv[nf] = MFMA(Ah8, Bh8, accv[nf]);
            accv[nf] = MFMA(Ah8, Bl8, accv[nf]);
            accv[nf] = MFMA(Al8, Bh8, accv[nf]);
        }
    }

    // ---- cross-wave reduce + aw write (D: row=lg*4+r=q, col=li=d) ----
#pragma unroll
    for (int nf = 0; nf < 4; ++nf)
#pragma unroll
        for (int r = 0; r < 4; ++r)
            obuf[(w * 16 + lg * 4 + r) * 68 + nf * 16 + li] = accv[nf][r];
    __syncthreads();
    {
        int row = threadIdx.x >> 4, d0 = (threadIdx.x & 15) * 4;
        float s0 = 0.f, s1 = 0.f, s2 = 0.f, s3 = 0.f;
#pragma unroll
        for (int ww = 0; ww < 4; ++ww) {
            float4 t = *(const float4*)&obuf[(ww * 16 + row) * 68 + d0];
            s0 += t.x; s1 += t.y; s2 += t.z; s3 += t.w;
        }
        ushort4 hv, lv; ushort h, lo;
        bf16_split(s0, h, lo); hv.x = h; lv.x = lo;
        bf16_split(s1, h, lo); hv.y = h; lv.y = lo;
        bf16_split(s2, h, lo); hv.z = h; lv.z = lo;
        bf16_split(s3, h, lo); hv.w = h; lv.w = lo;
        size_t o = ((size_t)(b * NTOK + qt * 16 + row)) * DMODEL + hd * DHEAD + d0;
        *(ushort4*)&awh[o] = hv;
        *(ushort4*)&awl[o] = lv;
    }
}

// ---------------------------------------------------------------------------
extern "C" void kernel_launch(void* const* d_in, const int* in_sizes, int n_in,
                              void* d_out, int out_size, void* d_ws, size_t ws_size,
                              hipStream_t stream)
{
    const float* x   = (const float*)d_in[0];
    const float* xyz = (const float*)d_in[1];
    const float* Wq  = (const float*)d_in[2];
    const float* bq  = (const float*)d_in[3];
    const float* Wk  = (const float*)d_in[4];
    const float* bk  = (const float*)d_in[5];
    const float* Wv  = (const float*)d_in[6];
    const float* bv  = (const float*)d_in[7];
    const float* Wo  = (const float*)d_in[8];
    const float* bo  = (const float*)d_in[9];
    const float* W1  = (const float*)d_in[10];
    const float* b1  = (const float*)d_in[11];
    const float* W2  = (const float*)d_in[12];
    const float* b2  = (const float*)d_in[13];

    const size_t OUT_ELEMS = (size_t)2 * NTOK * DMODEL;     // 2,097,152
    float* out   = (float*)d_out;
    float* attnO = out + OUT_ELEMS;                          // [B,H,N,N]

    // workspace layout (bytes)
    char* ws = (char*)d_ws;
    ushort* Wcth = (ushort*)(ws);                            //  6 MB [3072][1024]
    ushort* Wctl = (ushort*)(ws + 6291456);                  //  6 MB
    ushort* Woth = (ushort*)(ws + 12582912);                 //  2 MB [1024][1024]
    ushort* Wotl = (ushort*)(ws + 14680064);                 //  2 MB
    ushort* qh   = (ushort*)(ws + 16777216);                 //  4 MB [bh][n][64]
    ushort* ql   = (ushort*)(ws + 20971520);
    ushort* kh   = (ushort*)(ws + 25165824);
    ushort* kl   = (ushort*)(ws + 29360128);
    ushort* vth  = (ushort*)(ws + 33554432);                 //  4 MB [bh][64][n]
    ushort* vtl  = (ushort*)(ws + 37748736);
    ushort* xh   = (ushort*)(ws + 41943040);                 //  4 MB [2048][1024]
    ushort* xl   = (ushort*)(ws + 46137344);                 //  ends at 48 MB
    // aw aliases the x buffers (x is dead after the QKV GEMM)
    ushort* awh  = xh;
    ushort* awl  = xl;

    // 1) bias MLP -> attn region of d_out
    bias_kernel<<<dim3(4, 1024, 2), 256, 0, stream>>>(xyz, W1, b1, W2, b2, attnO);
    // 2) input conversions
    convx_kernel<<<dim3(2048), 256, 0, stream>>>(x, xh, xl);
    convw_kernel<<<dim3(16, 16, 4), 256, 0, stream>>>(Wq, Wk, Wv, Wo,
                                                      Wcth, Wctl, Woth, Wotl);
    // 3) fused QKV projection (M=2048, N=3072), 64x64 tiles
    mm_kernel<<<dim3(48, 32), 256, 0, stream>>>(xh, xl, Wcth, Wctl,
                                                bq, bk, bv, nullptr,
                                                qh, ql, kh, kl, vth, vtl, 1);
    // 4) fused scores + softmax + PV -> attnO (P) and aw (bf16 hi/lo)
    attn_fused_kernel<<<dim3(64, NHEADS, 2), 256, 0, stream>>>(
        qh, ql, kh, kl, vth, vtl, attnO, awh, awl);
    // 5) output projection (M=2048, N=1024), 64x64 tiles
    mm_kernel<<<dim3(16, 32), 256, 0, stream>>>(awh, awl, Woth, Wotl,
                                                bo, bo, bo, out,
                                                nullptr, nullptr, nullptr, nullptr,
                                                nullptr, nullptr, 0);
}